// Round 6
// baseline (106.296 us; speedup 1.0000x reference)
//
#include <hip/hip_runtime.h>

#define NN 1024
#define DD 128

// artanh(z)/z with reference-style clipping (z >= 0)
__device__ __forceinline__ float artanh_ratio(float z) {
  z = fminf(z, 1.0f - 1e-7f);
  if (z < 1e-4f) return 1.0f + z * z * (1.0f / 3.0f);
  return 0.5f * logf((1.0f + z) / (1.0f - z)) / z;
}

// ---------------- K1: per-node scalars ----------------
// nx2[i]=|x_i|^2 ; lft[i]=h_i*(x_i.w[:128]) ; rgt[i]=h_i*(x_i.w[128:])
__global__ __launch_bounds__(256) void k1_scalars(
    const float* __restrict__ x, const float* __restrict__ aw,
    float* __restrict__ nx2, float* __restrict__ lft, float* __restrict__ rgt) {
  const int row = blockIdx.x * 4 + (threadIdx.x >> 6);
  const int l = threadIdx.x & 63;
  const float* xr = x + row * DD;
  float x0 = xr[l], x1 = xr[l + 64];
  float sa = x0 * x0 + x1 * x1;
  float sb = x0 * aw[l] + x1 * aw[l + 64];
  float sc = x0 * aw[DD + l] + x1 * aw[DD + l + 64];
#pragma unroll
  for (int m = 1; m < 64; m <<= 1) {
    sa += __shfl_xor(sa, m, 64);
    sb += __shfl_xor(sb, m, 64);
    sc += __shfl_xor(sc, m, 64);
  }
  if (l == 0) {
    float pn = fmaxf(sqrtf(sa), 1e-15f);
    float h = artanh_ratio(pn);
    nx2[row] = sa;
    lft[row] = h * sb;
    rgt[row] = h * sc;
  }
}

// ---------------- K2: j-split pair+aggregate kernel ----------------
// Block (512 thr = 8 waves) owns ONE row i. Wave w handles j in
// [w*128, w*128+128) as 2 chunks of 64 (lane-per-j). V accumulated with
// lane owning d = {2l, 2l+1}; cross-wave reduce in LDS; epilogue fused.
__global__ __launch_bounds__(512) void k2_jsplit(
    const float* __restrict__ x, const float* __restrict__ adj,
    const float* __restrict__ bptr,
    const float* __restrict__ nx2, const float* __restrict__ lft,
    const float* __restrict__ rgt, float* __restrict__ out) {
  __shared__ __align__(16) float xi_lds[DD];
  __shared__ float vred0[8 * 64];
  __shared__ float vred1[8 * 64];
  __shared__ float sared[8];
  const int t = threadIdx.x;
  const int w = t >> 6;
  const int l = t & 63;
  const int row = blockIdx.x;

  if (t < DD) xi_lds[t] = x[row * DD + t];
  __syncthreads();

  const float attb = bptr[0];
  const float nx2i = nx2[row];
  const float lfti = lft[row];
  const float beta = 1.0f - nx2i;
  const float betac = fmaxf(beta, 1e-15f);

  float V0 = 0.0f, V1 = 0.0f, SA = 0.0f;

  for (int c = 0; c < 2; ++c) {
    const int j0 = w * 128 + c * 64;
    const int jj = j0 + l;
    // per-j precomputed scalars (coalesced)
    const float ny2 = nx2[jj];
    const float rgtj = rgt[jj];
    const float aj = adj[row * NN + jj];
    // s = x_i . x_j  (x_i broadcast from LDS; 2 partial chains for ILP)
    const float* xj = x + jj * DD;
    float sA = 0.0f, sB = 0.0f;
#pragma unroll
    for (int k8 = 0; k8 < DD / 8; ++k8) {
      const float4 bA = *(const float4*)(xj + k8 * 8);
      const float4 bB = *(const float4*)(xj + k8 * 8 + 4);
      const float4 aA = *(const float4*)(&xi_lds[k8 * 8]);
      const float4 aB = *(const float4*)(&xi_lds[k8 * 8 + 4]);
      sA = fmaf(aA.x, bA.x, fmaf(aA.y, bA.y, fmaf(aA.z, bA.z, fmaf(aA.w, bA.w, sA))));
      sB = fmaf(aB.x, bB.x, fmaf(aB.y, bB.y, fmaf(aB.z, bB.z, fmaf(aB.w, bB.w, sB))));
    }
    const float s = sA + sB;
    // pair scalars (c = 1)
    const float al = 1.0f - 2.0f * s + ny2;            // alpha_ij
    const float den = fmaxf(1.0f - 2.0f * s + nx2i * ny2, 1e-15f);
    float s2 = fmaxf(al * al * nx2i - 2.0f * al * beta * s + beta * beta * ny2, 0.0f);
    s2 = s2 / (den * den);                             // |sub|^2
    const float sn = fmaxf(sqrtf(s2), 1e-15f);
    const float G = betac * artanh_ratio(sn);
    const float sig = 1.0f / (1.0f + expf(-(lfti + rgtj + attb)));
    const float u = sig * aj * G / den;
    SA = fmaf(u, al, SA);

    // V[d] += u_j * x_j[d] ; lane owns d = {2l, 2l+1}
#pragma unroll 16
    for (int jq = 0; jq < 64; ++jq) {
      const float uq = __shfl(u, jq, 64);
      const float2 xv = *(const float2*)&x[(j0 + jq) * DD + 2 * l];
      V0 = fmaf(uq, xv.x, V0);
      V1 = fmaf(uq, xv.y, V1);
    }
  }

  // SA: wave-reduce then cross-wave
#pragma unroll
  for (int m = 1; m < 64; m <<= 1) SA += __shfl_xor(SA, m, 64);
  if (l == 0) sared[w] = SA;
  vred0[w * 64 + l] = V0;
  vred1[w * 64 + l] = V1;
  __syncthreads();

  // all waves compute identical epilogue; wave 0 stores
  float v0 = 0.0f, v1 = 0.0f;
#pragma unroll
  for (int ww = 0; ww < 8; ++ww) {
    v0 += vred0[ww * 64 + l];
    v1 += vred1[ww * 64 + l];
  }
  float sa = sared[0] + sared[1] + sared[2] + sared[3] +
             sared[4] + sared[5] + sared[6] + sared[7];

  const float xi0 = xi_lds[2 * l];
  const float xi1 = xi_lds[2 * l + 1];
  // support_t = beta*V - SA*x_i ; then expmap + proj
  const float u0 = beta * v0 - sa * xi0;
  const float u1 = beta * v1 - sa * xi1;
  float p0 = u0 * u0 + u1 * u1;    // -> |u|^2
  float p1 = xi0 * u0 + xi1 * u1;  // -> x.u
#pragma unroll
  for (int m = 1; m < 64; m <<= 1) {
    p0 += __shfl_xor(p0, m, 64);
    p1 += __shfl_xor(p1, m, 64);
  }
  const float un = fmaxf(sqrtf(p0), 1e-15f);
  const float lam = 2.0f / betac;
  const float tau = tanhf(0.5f * lam * un) / un;   // second = tau*u
  const float y2 = tau * tau * p0;                 // |second|^2
  const float xy = tau * p1;                       // x.second
  const float numx = 1.0f + 2.0f * xy + y2;
  const float dene = fmaxf(1.0f + 2.0f * xy + nx2i * y2, 1e-15f);
  float r0 = (numx * xi0 + beta * tau * u0) / dene;
  float r1 = (numx * xi1 + beta * tau * u1) / dene;
  const float n2 = numx * numx * nx2i + 2.0f * numx * beta * xy + beta * beta * y2;
  const float n = fmaxf(sqrtf(n2) / dene, 1e-15f);
  const float maxn = 1.0f - 4e-3f;  // (1-PROJ_EPS)/sqrt(c)
  if (n > maxn) {
    const float sc = maxn / n;
    r0 *= sc;
    r1 *= sc;
  }
  if (w == 0) {
    out[row * DD + 2 * l] = r0;
    out[row * DD + 2 * l + 1] = r1;
  }
}

// ---------------- Fallback: round-5 fused kernel (proven) ----------------
__global__ __launch_bounds__(256) void hypagg_fused(
    const float* __restrict__ x, const float* __restrict__ adj,
    const float* __restrict__ aw, const float* __restrict__ bptr,
    float* __restrict__ out) {
  __shared__ __align__(16) float xi_lds[4 * DD];
  __shared__ __align__(16) float w2_lds[DD];
  const int t = threadIdx.x;
  const int w = t >> 6;
  const int l = t & 63;
  const int row = blockIdx.x * 4 + w;

  xi_lds[t] = x[blockIdx.x * 4 * DD + t];
  xi_lds[t + 256] = x[blockIdx.x * 4 * DD + t + 256];
  if (t < DD) w2_lds[t] = aw[DD + t];
  __syncthreads();

  const float attb = bptr[0];
  const float* xi = &xi_lds[w * DD];
  const float xi0 = xi[l];
  const float xi1 = xi[l + 64];

  float ra = xi0 * xi0 + xi1 * xi1;
  float rb = xi0 * aw[l] + xi1 * aw[l + 64];
#pragma unroll
  for (int m = 1; m < 64; m <<= 1) {
    ra += __shfl_xor(ra, m, 64);
    rb += __shfl_xor(rb, m, 64);
  }
  const float nx2i = ra;
  const float beta = 1.0f - nx2i;
  const float betac = fmaxf(beta, 1e-15f);
  const float hi = artanh_ratio(fmaxf(sqrtf(nx2i), 1e-15f));
  const float lfti = hi * rb;

  float V0 = 0.0f, V1 = 0.0f, SA = 0.0f;

  for (int j0 = 0; j0 < NN; j0 += 64) {
    const int jj = j0 + l;
    const float* xj = x + jj * DD;
    float s = 0.0f, ny2 = 0.0f, rj = 0.0f;
#pragma unroll 8
    for (int k4 = 0; k4 < DD / 4; ++k4) {
      const float4 b4 = *(const float4*)(xj + k4 * 4);
      const float4 a4 = *(const float4*)(xi + k4 * 4);
      const float4 w4 = *(const float4*)(&w2_lds[k4 * 4]);
      s   = fmaf(a4.x, b4.x, fmaf(a4.y, b4.y, fmaf(a4.z, b4.z, fmaf(a4.w, b4.w, s))));
      ny2 = fmaf(b4.x, b4.x, fmaf(b4.y, b4.y, fmaf(b4.z, b4.z, fmaf(b4.w, b4.w, ny2))));
      rj  = fmaf(w4.x, b4.x, fmaf(w4.y, b4.y, fmaf(w4.z, b4.z, fmaf(w4.w, b4.w, rj))));
    }
    const float hj = artanh_ratio(fmaxf(sqrtf(ny2), 1e-15f));
    const float rgtj = hj * rj;
    const float al = 1.0f - 2.0f * s + ny2;
    const float den = fmaxf(1.0f - 2.0f * s + nx2i * ny2, 1e-15f);
    float s2 = fmaxf(al * al * nx2i - 2.0f * al * beta * s + beta * beta * ny2, 0.0f);
    s2 = s2 / (den * den);
    const float sn = fmaxf(sqrtf(s2), 1e-15f);
    const float G = betac * artanh_ratio(sn);
    const float sig = 1.0f / (1.0f + expf(-(lfti + rgtj + attb)));
    const float u = sig * adj[row * NN + jj] * G / den;
    SA = fmaf(u, al, SA);
#pragma unroll 16
    for (int jq = 0; jq < 64; ++jq) {
      const float uq = __shfl(u, jq, 64);
      const float xd0 = x[(j0 + jq) * DD + l];
      const float xd1 = x[(j0 + jq) * DD + l + 64];
      V0 = fmaf(uq, xd0, V0);
      V1 = fmaf(uq, xd1, V1);
    }
  }

#pragma unroll
  for (int m = 1; m < 64; m <<= 1) SA += __shfl_xor(SA, m, 64);

  const float u0 = beta * V0 - SA * xi0;
  const float u1 = beta * V1 - SA * xi1;
  float p0 = u0 * u0 + u1 * u1;
  float p1 = xi0 * u0 + xi1 * u1;
#pragma unroll
  for (int m = 1; m < 64; m <<= 1) {
    p0 += __shfl_xor(p0, m, 64);
    p1 += __shfl_xor(p1, m, 64);
  }
  const float un = fmaxf(sqrtf(p0), 1e-15f);
  const float lam = 2.0f / betac;
  const float tau = tanhf(0.5f * lam * un) / un;
  const float y2 = tau * tau * p0;
  const float xy = tau * p1;
  const float numx = 1.0f + 2.0f * xy + y2;
  const float dene = fmaxf(1.0f + 2.0f * xy + nx2i * y2, 1e-15f);
  float r0 = (numx * xi0 + beta * tau * u0) / dene;
  float r1 = (numx * xi1 + beta * tau * u1) / dene;
  const float n2 = numx * numx * nx2i + 2.0f * numx * beta * xy + beta * beta * y2;
  const float n = fmaxf(sqrtf(n2) / dene, 1e-15f);
  const float maxn = 1.0f - 4e-3f;
  if (n > maxn) {
    const float sc = maxn / n;
    r0 *= sc;
    r1 *= sc;
  }
  out[row * DD + l] = r0;
  out[row * DD + l + 64] = r1;
}

extern "C" void kernel_launch(void* const* d_in, const int* in_sizes, int n_in,
                              void* d_out, int out_size, void* d_ws, size_t ws_size,
                              hipStream_t stream) {
  // Bind inputs BY SIZE (unique: x=131072, adj=1048576, att_w=256, att_b=1)
  const float* x = nullptr;
  const float* adj = nullptr;
  const float* aw = nullptr;
  const float* ab = nullptr;
  for (int i = 0; i < n_in; ++i) {
    switch (in_sizes[i]) {
      case NN * DD:  x   = (const float*)d_in[i]; break;
      case NN * NN:  adj = (const float*)d_in[i]; break;
      case 2 * DD:   aw  = (const float*)d_in[i]; break;
      case 1:        ab  = (const float*)d_in[i]; break;
      default: break;
    }
  }
  float* out = (float*)d_out;

  if (ws_size >= 3 * NN * sizeof(float)) {
    float* nx2 = (float*)d_ws;       // [N]
    float* lft = nx2 + NN;           // [N]
    float* rgt = lft + NN;           // [N]
    hipLaunchKernelGGL(k1_scalars, dim3(NN / 4), dim3(256), 0, stream,
                       x, aw, nx2, lft, rgt);
    hipLaunchKernelGGL(k2_jsplit, dim3(NN), dim3(512), 0, stream,
                       x, adj, ab, nx2, lft, rgt, out);
  } else {
    hipLaunchKernelGGL(hypagg_fused, dim3(NN / 4), dim3(256), 0, stream,
                       x, adj, aw, ab, out);
  }
}

// Round 7
// 38.934 us; speedup vs baseline: 2.7302x; 2.7302x over previous
//
#include <hip/hip_runtime.h>

#define NN 1024
#define DD 128

// artanh(z)/z with reference-style clipping (z >= 0)
__device__ __forceinline__ float artanh_ratio(float z) {
  z = fminf(z, 1.0f - 1e-7f);
  if (z < 1e-4f) return 1.0f + z * z * (1.0f / 3.0f);
  return 0.5f * logf((1.0f + z) / (1.0f - z)) / z;
}

// ---------------- K1: per-node scalars (proven) ----------------
__global__ __launch_bounds__(256) void k1_scalars(
    const float* __restrict__ x, const float* __restrict__ aw,
    float* __restrict__ nx2, float* __restrict__ lft, float* __restrict__ rgt) {
  const int row = blockIdx.x * 4 + (threadIdx.x >> 6);
  const int l = threadIdx.x & 63;
  const float* xr = x + row * DD;
  float x0 = xr[l], x1 = xr[l + 64];
  float sa = x0 * x0 + x1 * x1;
  float sb = x0 * aw[l] + x1 * aw[l + 64];
  float sc = x0 * aw[DD + l] + x1 * aw[DD + l + 64];
#pragma unroll
  for (int m = 1; m < 64; m <<= 1) {
    sa += __shfl_xor(sa, m, 64);
    sb += __shfl_xor(sb, m, 64);
    sc += __shfl_xor(sc, m, 64);
  }
  if (l == 0) {
    float pn = fmaxf(sqrtf(sa), 1e-15f);
    float h = artanh_ratio(pn);
    nx2[row] = sa;
    lft[row] = h * sb;
    rgt[row] = h * sc;
  }
}

// ---------------- K2: tiled S-GEMM + pair epilogue ----------------
// 64x64 tile per block; k-major LDS panels [128k][64r] (32 KB each).
// Thread (tx,ty) computes 4x4 pairs; writes W=u and PA=sum(u*alpha) per tile.
__global__ __launch_bounds__(256) void k2_pairs(
    const float* __restrict__ x, const float* __restrict__ adj,
    const float* __restrict__ bptr,
    const float* __restrict__ nx2, const float* __restrict__ lft,
    const float* __restrict__ rgt,
    float* __restrict__ W, float* __restrict__ PA) {
  __shared__ __align__(16) float xiT[DD * 64];
  __shared__ __align__(16) float xjT[DD * 64];
  const int t = threadIdx.x;
  const int bi = blockIdx.y, bj = blockIdx.x;
  {
    const int r = t & 63;
    const int kq = t >> 6;  // k-quarter (32 k each)
    const float* si = x + (bi * 64 + r) * DD + kq * 32;
    const float* sj = x + (bj * 64 + r) * DD + kq * 32;
#pragma unroll
    for (int m = 0; m < 8; ++m) {
      const int k0 = kq * 32 + m * 4;
      const float4 vi = *(const float4*)(si + m * 4);
      const float4 vj = *(const float4*)(sj + m * 4);
      xiT[(k0 + 0) * 64 + r] = vi.x;
      xiT[(k0 + 1) * 64 + r] = vi.y;
      xiT[(k0 + 2) * 64 + r] = vi.z;
      xiT[(k0 + 3) * 64 + r] = vi.w;
      xjT[(k0 + 0) * 64 + r] = vj.x;
      xjT[(k0 + 1) * 64 + r] = vj.y;
      xjT[(k0 + 2) * 64 + r] = vj.z;
      xjT[(k0 + 3) * 64 + r] = vj.w;
    }
  }
  __syncthreads();
  const int tx = t & 15, ty = t >> 4;
  float acc[4][4] = {};
#pragma unroll 2
  for (int k = 0; k < DD; ++k) {
    const float4 a4 = *(const float4*)&xiT[k * 64 + ty * 4];
    const float4 b4 = *(const float4*)&xjT[k * 64 + tx * 4];
    const float aa[4] = {a4.x, a4.y, a4.z, a4.w};
    const float bb[4] = {b4.x, b4.y, b4.z, b4.w};
#pragma unroll
    for (int i = 0; i < 4; ++i)
#pragma unroll
      for (int j = 0; j < 4; ++j) acc[i][j] = fmaf(aa[i], bb[j], acc[i][j]);
  }
  // pair epilogue (formulas proven in rounds 5/6)
  const float attb = bptr[0];
  const int gi0 = bi * 64 + ty * 4;
  const int gj0 = bj * 64 + tx * 4;
  float ny2v[4], rv[4];
#pragma unroll
  for (int j = 0; j < 4; ++j) { ny2v[j] = nx2[gj0 + j]; rv[j] = rgt[gj0 + j]; }
  float sua[4];
#pragma unroll
  for (int i = 0; i < 4; ++i) {
    const int gi = gi0 + i;
    const float xi2 = nx2[gi];
    const float li = lft[gi];
    const float beta = 1.0f - xi2;
    const float betac = fmaxf(beta, 1e-15f);
    const float4 aj4 = *(const float4*)&adj[gi * NN + gj0];
    const float av[4] = {aj4.x, aj4.y, aj4.z, aj4.w};
    float u4[4];
    float ua = 0.0f;
#pragma unroll
    for (int j = 0; j < 4; ++j) {
      const float s = acc[i][j];
      const float al = 1.0f - 2.0f * s + ny2v[j];                      // alpha
      const float den = fmaxf(1.0f - 2.0f * s + xi2 * ny2v[j], 1e-15f);
      float s2 = fmaxf(al * al * xi2 - 2.0f * al * beta * s + beta * beta * ny2v[j], 0.0f);
      s2 = s2 / (den * den);                                            // |sub|^2
      const float sn = fmaxf(sqrtf(s2), 1e-15f);
      const float G = betac * artanh_ratio(sn);
      const float sig = 1.0f / (1.0f + expf(-(li + rv[j] + attb)));
      const float u = sig * av[j] * G / den;
      u4[j] = u;
      ua = fmaf(u, al, ua);
    }
    float4 st; st.x = u4[0]; st.y = u4[1]; st.z = u4[2]; st.w = u4[3];
    *(float4*)&W[gi * NN + gj0] = st;
    sua[i] = ua;
  }
#pragma unroll
  for (int m = 1; m < 16; m <<= 1) {
#pragma unroll
    for (int i = 0; i < 4; ++i) sua[i] += __shfl_xor(sua[i], m, 64);
  }
  if (tx == 0) {
#pragma unroll
    for (int i = 0; i < 4; ++i) PA[(gi0 + i) * 16 + bj] = sua[i];
  }
}

// ---------------- K3: V-partials GEMM ----------------
// Block (kt, rt): rows rt*64..+63, contraction chunk j = kt*64..+63.
// uT [64j][64i] (16 KB) transposed; xT [64j][128d] row-major (32 KB).
// Thread (tx,ty): acc[4 rows][8 dims].
__global__ __launch_bounds__(256) void k3_vpart(
    const float* __restrict__ x, const float* __restrict__ W,
    float* __restrict__ Vp) {
  __shared__ __align__(16) float uT[64 * 64];
  __shared__ __align__(16) float xT[64 * DD];
  const int t = threadIdx.x;
  const int kt = blockIdx.x, rt = blockIdx.y;
  {
    const int r = t & 63;
    const int kq = t >> 6;  // 16 k each
#pragma unroll
    for (int m = 0; m < 4; ++m) {
      const int k0 = kq * 16 + m * 4;
      const float4 v = *(const float4*)&W[(rt * 64 + r) * NN + kt * 64 + k0];
      uT[(k0 + 0) * 64 + r] = v.x;
      uT[(k0 + 1) * 64 + r] = v.y;
      uT[(k0 + 2) * 64 + r] = v.z;
      uT[(k0 + 3) * 64 + r] = v.w;
    }
#pragma unroll
    for (int p = 0; p < 8; ++p) {
      const int flat = p * 1024 + t * 4;
      *(float4*)&xT[flat] = *(const float4*)&x[kt * 64 * DD + flat];
    }
  }
  __syncthreads();
  const int tx = t & 15, ty = t >> 4;
  float acc[4][8] = {};
#pragma unroll 2
  for (int k = 0; k < 64; ++k) {
    const float4 a4 = *(const float4*)&uT[k * 64 + ty * 4];
    const float4 b0 = *(const float4*)&xT[k * DD + tx * 8];
    const float4 b1 = *(const float4*)&xT[k * DD + tx * 8 + 4];
    const float aa[4] = {a4.x, a4.y, a4.z, a4.w};
    const float bb[8] = {b0.x, b0.y, b0.z, b0.w, b1.x, b1.y, b1.z, b1.w};
#pragma unroll
    for (int i = 0; i < 4; ++i)
#pragma unroll
      for (int m = 0; m < 8; ++m) acc[i][m] = fmaf(aa[i], bb[m], acc[i][m]);
  }
#pragma unroll
  for (int i = 0; i < 4; ++i) {
    const int row = rt * 64 + ty * 4 + i;
    float4 s0; s0.x = acc[i][0]; s0.y = acc[i][1]; s0.z = acc[i][2]; s0.w = acc[i][3];
    float4 s1; s1.x = acc[i][4]; s1.y = acc[i][5]; s1.z = acc[i][6]; s1.w = acc[i][7];
    *(float4*)&Vp[(size_t)kt * NN * DD + row * DD + tx * 8] = s0;
    *(float4*)&Vp[(size_t)kt * NN * DD + row * DD + tx * 8 + 4] = s1;
  }
}

// ---------------- K4: reduce partials + expmap/proj epilogue (proven) ----------------
__global__ __launch_bounds__(256) void k4_final(
    const float* __restrict__ x, const float* __restrict__ Vp,
    const float* __restrict__ PA, const float* __restrict__ nx2,
    float* __restrict__ out) {
  const int t = threadIdx.x;
  const int w = t >> 6;
  const int l = t & 63;
  const int row = blockIdx.x * 4 + w;

  float v0 = 0.0f, v1 = 0.0f;
#pragma unroll
  for (int kt = 0; kt < 16; ++kt) {
    const float2 vv = *(const float2*)&Vp[(size_t)kt * NN * DD + row * DD + 2 * l];
    v0 += vv.x;
    v1 += vv.y;
  }
  float sa = (l < 16) ? PA[row * 16 + l] : 0.0f;
#pragma unroll
  for (int m = 1; m < 64; m <<= 1) sa += __shfl_xor(sa, m, 64);

  const float nx2i = nx2[row];
  const float beta = 1.0f - nx2i;
  const float betac = fmaxf(beta, 1e-15f);
  const float2 xv = *(const float2*)&x[row * DD + 2 * l];
  const float xi0 = xv.x, xi1 = xv.y;
  // support_t = beta*V - SA*x_i ; expmap + proj
  const float u0 = beta * v0 - sa * xi0;
  const float u1 = beta * v1 - sa * xi1;
  float p0 = u0 * u0 + u1 * u1;
  float p1 = xi0 * u0 + xi1 * u1;
#pragma unroll
  for (int m = 1; m < 64; m <<= 1) {
    p0 += __shfl_xor(p0, m, 64);
    p1 += __shfl_xor(p1, m, 64);
  }
  const float un = fmaxf(sqrtf(p0), 1e-15f);
  const float lam = 2.0f / betac;
  const float tau = tanhf(0.5f * lam * un) / un;
  const float y2 = tau * tau * p0;
  const float xy = tau * p1;
  const float numx = 1.0f + 2.0f * xy + y2;
  const float dene = fmaxf(1.0f + 2.0f * xy + nx2i * y2, 1e-15f);
  float r0 = (numx * xi0 + beta * tau * u0) / dene;
  float r1 = (numx * xi1 + beta * tau * u1) / dene;
  const float n2 = numx * numx * nx2i + 2.0f * numx * beta * xy + beta * beta * y2;
  const float n = fmaxf(sqrtf(n2) / dene, 1e-15f);
  const float maxn = 1.0f - 4e-3f;
  if (n > maxn) {
    const float sc = maxn / n;
    r0 *= sc;
    r1 *= sc;
  }
  float2 ro; ro.x = r0; ro.y = r1;
  *(float2*)&out[row * DD + 2 * l] = ro;
}

// ---------------- Fallback: round-5 fused kernel (proven, 90 us) ----------------
__global__ __launch_bounds__(256) void hypagg_fused(
    const float* __restrict__ x, const float* __restrict__ adj,
    const float* __restrict__ aw, const float* __restrict__ bptr,
    float* __restrict__ out) {
  __shared__ __align__(16) float xi_lds[4 * DD];
  __shared__ __align__(16) float w2_lds[DD];
  const int t = threadIdx.x;
  const int w = t >> 6;
  const int l = t & 63;
  const int row = blockIdx.x * 4 + w;

  xi_lds[t] = x[blockIdx.x * 4 * DD + t];
  xi_lds[t + 256] = x[blockIdx.x * 4 * DD + t + 256];
  if (t < DD) w2_lds[t] = aw[DD + t];
  __syncthreads();

  const float attb = bptr[0];
  const float* xi = &xi_lds[w * DD];
  const float xi0 = xi[l];
  const float xi1 = xi[l + 64];

  float ra = xi0 * xi0 + xi1 * xi1;
  float rb = xi0 * aw[l] + xi1 * aw[l + 64];
#pragma unroll
  for (int m = 1; m < 64; m <<= 1) {
    ra += __shfl_xor(ra, m, 64);
    rb += __shfl_xor(rb, m, 64);
  }
  const float nx2i = ra;
  const float beta = 1.0f - nx2i;
  const float betac = fmaxf(beta, 1e-15f);
  const float hi = artanh_ratio(fmaxf(sqrtf(nx2i), 1e-15f));
  const float lfti = hi * rb;

  float V0 = 0.0f, V1 = 0.0f, SA = 0.0f;

  for (int j0 = 0; j0 < NN; j0 += 64) {
    const int jj = j0 + l;
    const float* xj = x + jj * DD;
    float s = 0.0f, ny2 = 0.0f, rj = 0.0f;
#pragma unroll 8
    for (int k4 = 0; k4 < DD / 4; ++k4) {
      const float4 b4 = *(const float4*)(xj + k4 * 4);
      const float4 a4 = *(const float4*)(xi + k4 * 4);
      const float4 w4 = *(const float4*)(&w2_lds[k4 * 4]);
      s   = fmaf(a4.x, b4.x, fmaf(a4.y, b4.y, fmaf(a4.z, b4.z, fmaf(a4.w, b4.w, s))));
      ny2 = fmaf(b4.x, b4.x, fmaf(b4.y, b4.y, fmaf(b4.z, b4.z, fmaf(b4.w, b4.w, ny2))));
      rj  = fmaf(w4.x, b4.x, fmaf(w4.y, b4.y, fmaf(w4.z, b4.z, fmaf(w4.w, b4.w, rj))));
    }
    const float hj = artanh_ratio(fmaxf(sqrtf(ny2), 1e-15f));
    const float rgtj = hj * rj;
    const float al = 1.0f - 2.0f * s + ny2;
    const float den = fmaxf(1.0f - 2.0f * s + nx2i * ny2, 1e-15f);
    float s2 = fmaxf(al * al * nx2i - 2.0f * al * beta * s + beta * beta * ny2, 0.0f);
    s2 = s2 / (den * den);
    const float sn = fmaxf(sqrtf(s2), 1e-15f);
    const float G = betac * artanh_ratio(sn);
    const float sig = 1.0f / (1.0f + expf(-(lfti + rgtj + attb)));
    const float u = sig * adj[row * NN + jj] * G / den;
    SA = fmaf(u, al, SA);
#pragma unroll 16
    for (int jq = 0; jq < 64; ++jq) {
      const float uq = __shfl(u, jq, 64);
      const float xd0 = x[(j0 + jq) * DD + l];
      const float xd1 = x[(j0 + jq) * DD + l + 64];
      V0 = fmaf(uq, xd0, V0);
      V1 = fmaf(uq, xd1, V1);
    }
  }

#pragma unroll
  for (int m = 1; m < 64; m <<= 1) SA += __shfl_xor(SA, m, 64);

  const float u0 = beta * V0 - SA * xi0;
  const float u1 = beta * V1 - SA * xi1;
  float p0 = u0 * u0 + u1 * u1;
  float p1 = xi0 * u0 + xi1 * u1;
#pragma unroll
  for (int m = 1; m < 64; m <<= 1) {
    p0 += __shfl_xor(p0, m, 64);
    p1 += __shfl_xor(p1, m, 64);
  }
  const float un = fmaxf(sqrtf(p0), 1e-15f);
  const float lam = 2.0f / betac;
  const float tau = tanhf(0.5f * lam * un) / un;
  const float y2 = tau * tau * p0;
  const float xy = tau * p1;
  const float numx = 1.0f + 2.0f * xy + y2;
  const float dene = fmaxf(1.0f + 2.0f * xy + nx2i * y2, 1e-15f);
  float r0 = (numx * xi0 + beta * tau * u0) / dene;
  float r1 = (numx * xi1 + beta * tau * u1) / dene;
  const float n2 = numx * numx * nx2i + 2.0f * numx * beta * xy + beta * beta * y2;
  const float n = fmaxf(sqrtf(n2) / dene, 1e-15f);
  const float maxn = 1.0f - 4e-3f;
  if (n > maxn) {
    const float sc = maxn / n;
    r0 *= sc;
    r1 *= sc;
  }
  out[row * DD + l] = r0;
  out[row * DD + l + 64] = r1;
}

extern "C" void kernel_launch(void* const* d_in, const int* in_sizes, int n_in,
                              void* d_out, int out_size, void* d_ws, size_t ws_size,
                              hipStream_t stream) {
  // Bind inputs BY SIZE (unique: x=131072, adj=1048576, att_w=256, att_b=1)
  const float* x = nullptr;
  const float* adj = nullptr;
  const float* aw = nullptr;
  const float* ab = nullptr;
  for (int i = 0; i < n_in; ++i) {
    switch (in_sizes[i]) {
      case NN * DD:  x   = (const float*)d_in[i]; break;
      case NN * NN:  adj = (const float*)d_in[i]; break;
      case 2 * DD:   aw  = (const float*)d_in[i]; break;
      case 1:        ab  = (const float*)d_in[i]; break;
      default: break;
    }
  }
  float* out = (float*)d_out;

  // ws layout: W [N*N] | Vp [16*N*D] | PA [N*16] | nx2,lft,rgt [3*N]
  const size_t need = ((size_t)NN * NN + 16 * (size_t)NN * DD + NN * 16 + 3 * NN) * sizeof(float);
  if (ws_size >= need) {
    float* W   = (float*)d_ws;
    float* Vp  = W + (size_t)NN * NN;
    float* PA  = Vp + 16 * (size_t)NN * DD;
    float* nx2 = PA + NN * 16;
    float* lft = nx2 + NN;
    float* rgt = lft + NN;
    hipLaunchKernelGGL(k1_scalars, dim3(NN / 4), dim3(256), 0, stream,
                       x, aw, nx2, lft, rgt);
    hipLaunchKernelGGL(k2_pairs, dim3(16, 16), dim3(256), 0, stream,
                       x, adj, ab, nx2, lft, rgt, W, PA);
    hipLaunchKernelGGL(k3_vpart, dim3(16, 16), dim3(256), 0, stream, x, W, Vp);
    hipLaunchKernelGGL(k4_final, dim3(NN / 4), dim3(256), 0, stream,
                       x, Vp, PA, nx2, out);
  } else {
    hipLaunchKernelGGL(hypagg_fused, dim3(NN / 4), dim3(256), 0, stream,
                       x, adj, aw, ab, out);
  }
}

// Round 8
// 35.613 us; speedup vs baseline: 2.9848x; 1.0933x over previous
//
#include <hip/hip_runtime.h>

#define NN 1024
#define DD 128
#define LDU 68  // uT k-stride in k3: 68*4B=272B, 16B-aligned, bank-spread

// artanh(z)/z with reference-style clipping (z >= 0)
__device__ __forceinline__ float artanh_ratio(float z) {
  z = fminf(z, 1.0f - 1e-7f);
  if (z < 1e-4f) return 1.0f + z * z * (1.0f / 3.0f);
  return 0.5f * logf((1.0f + z) / (1.0f - z)) / z;
}

// ---------------- K1: per-node scalars (proven) ----------------
__global__ __launch_bounds__(256) void k1_scalars(
    const float* __restrict__ x, const float* __restrict__ aw,
    float* __restrict__ nx2, float* __restrict__ lft, float* __restrict__ rgt) {
  const int row = blockIdx.x * 4 + (threadIdx.x >> 6);
  const int l = threadIdx.x & 63;
  const float* xr = x + row * DD;
  float x0 = xr[l], x1 = xr[l + 64];
  float sa = x0 * x0 + x1 * x1;
  float sb = x0 * aw[l] + x1 * aw[l + 64];
  float sc = x0 * aw[DD + l] + x1 * aw[DD + l + 64];
#pragma unroll
  for (int m = 1; m < 64; m <<= 1) {
    sa += __shfl_xor(sa, m, 64);
    sb += __shfl_xor(sb, m, 64);
    sc += __shfl_xor(sc, m, 64);
  }
  if (l == 0) {
    float pn = fmaxf(sqrtf(sa), 1e-15f);
    float h = artanh_ratio(pn);
    nx2[row] = sa;
    lft[row] = h * sb;
    rgt[row] = h * sc;
  }
}

// ---------------- K2: tiled S-GEMM + pair epilogue ----------------
// 64x64 tile; k-major LDS panels. Inner loop batches 4 k-steps of LDS reads
// (8 independent ds_read_b128 in flight) before the 64 FMAs -> ILP hides
// LDS latency at 1 wave/SIMD occupancy.
__global__ __launch_bounds__(256) void k2_pairs(
    const float* __restrict__ x, const float* __restrict__ adj,
    const float* __restrict__ bptr,
    const float* __restrict__ nx2, const float* __restrict__ lft,
    const float* __restrict__ rgt,
    float* __restrict__ W, float* __restrict__ PA) {
  __shared__ __align__(16) float xiT[DD * 64];
  __shared__ __align__(16) float xjT[DD * 64];
  const int t = threadIdx.x;
  const int bi = blockIdx.y, bj = blockIdx.x;
  {
    const int r = t & 63;
    const int kq = t >> 6;  // k-quarter (32 k each)
    const float* si = x + (bi * 64 + r) * DD + kq * 32;
    const float* sj = x + (bj * 64 + r) * DD + kq * 32;
#pragma unroll
    for (int m = 0; m < 8; ++m) {
      const int k0 = kq * 32 + m * 4;
      const float4 vi = *(const float4*)(si + m * 4);
      const float4 vj = *(const float4*)(sj + m * 4);
      xiT[(k0 + 0) * 64 + r] = vi.x;
      xiT[(k0 + 1) * 64 + r] = vi.y;
      xiT[(k0 + 2) * 64 + r] = vi.z;
      xiT[(k0 + 3) * 64 + r] = vi.w;
      xjT[(k0 + 0) * 64 + r] = vj.x;
      xjT[(k0 + 1) * 64 + r] = vj.y;
      xjT[(k0 + 2) * 64 + r] = vj.z;
      xjT[(k0 + 3) * 64 + r] = vj.w;
    }
  }
  __syncthreads();
  const int tx = t & 15, ty = t >> 4;
  float acc[4][4] = {};
#pragma unroll 2
  for (int kb = 0; kb < DD; kb += 4) {
    float4 A[4], B[4];
#pragma unroll
    for (int q = 0; q < 4; ++q) {
      A[q] = *(const float4*)&xiT[(kb + q) * 64 + ty * 4];
      B[q] = *(const float4*)&xjT[(kb + q) * 64 + tx * 4];
    }
#pragma unroll
    for (int q = 0; q < 4; ++q) {
      const float aa[4] = {A[q].x, A[q].y, A[q].z, A[q].w};
      const float bb[4] = {B[q].x, B[q].y, B[q].z, B[q].w};
#pragma unroll
      for (int i = 0; i < 4; ++i)
#pragma unroll
        for (int j = 0; j < 4; ++j) acc[i][j] = fmaf(aa[i], bb[j], acc[i][j]);
    }
  }
  // pair epilogue (formulas proven in rounds 5-7)
  const float attb = bptr[0];
  const int gi0 = bi * 64 + ty * 4;
  const int gj0 = bj * 64 + tx * 4;
  float ny2v[4], rv[4];
#pragma unroll
  for (int j = 0; j < 4; ++j) { ny2v[j] = nx2[gj0 + j]; rv[j] = rgt[gj0 + j]; }
  float sua[4];
#pragma unroll
  for (int i = 0; i < 4; ++i) {
    const int gi = gi0 + i;
    const float xi2 = nx2[gi];
    const float li = lft[gi];
    const float beta = 1.0f - xi2;
    const float betac = fmaxf(beta, 1e-15f);
    const float4 aj4 = *(const float4*)&adj[gi * NN + gj0];
    const float av[4] = {aj4.x, aj4.y, aj4.z, aj4.w};
    float u4[4];
    float ua = 0.0f;
#pragma unroll
    for (int j = 0; j < 4; ++j) {
      const float s = acc[i][j];
      const float al = 1.0f - 2.0f * s + ny2v[j];                      // alpha
      const float den = fmaxf(1.0f - 2.0f * s + xi2 * ny2v[j], 1e-15f);
      float s2 = fmaxf(al * al * xi2 - 2.0f * al * beta * s + beta * beta * ny2v[j], 0.0f);
      s2 = s2 / (den * den);                                            // |sub|^2
      const float sn = fmaxf(sqrtf(s2), 1e-15f);
      const float G = betac * artanh_ratio(sn);
      const float sig = 1.0f / (1.0f + expf(-(li + rv[j] + attb)));
      const float u = sig * av[j] * G / den;
      u4[j] = u;
      ua = fmaf(u, al, ua);
    }
    float4 st; st.x = u4[0]; st.y = u4[1]; st.z = u4[2]; st.w = u4[3];
    *(float4*)&W[gi * NN + gj0] = st;
    sua[i] = ua;
  }
#pragma unroll
  for (int m = 1; m < 16; m <<= 1) {
#pragma unroll
    for (int i = 0; i < 4; ++i) sua[i] += __shfl_xor(sua[i], m, 64);
  }
  if (tx == 0) {
#pragma unroll
    for (int i = 0; i < 4; ++i) PA[(gi0 + i) * 16 + bj] = sua[i];
  }
}

// ---------------- K3: V-partials GEMM (512 thr, VALU-bound) ----------------
// Block (kt, rt): rows rt*64..+63, j-chunk kt*64..+63.
// uT [64k][64r] stride-68; xT [64j][128d] row-major.
// Wave w: d-half = w&1; lane: tx = d-quad, ly = row-group; 4 rows x 4 dims.
__global__ __launch_bounds__(512) void k3_vpart(
    const float* __restrict__ x, const float* __restrict__ W,
    float* __restrict__ Vp) {
  __shared__ __align__(16) float uT[64 * LDU];
  __shared__ __align__(16) float xT[64 * DD];
  const int t = threadIdx.x;
  const int kt = blockIdx.x, rt = blockIdx.y;
  // stage uT: coalesced W reads (8 rows x 128B per wave), transposed write
  {
    const int r = t >> 3;          // 0..63
    const int cb = (t & 7) * 4;    // 0,4,..,28
    const float* wrow = &W[(size_t)(rt * 64 + r) * NN + kt * 64];
    const float4 v0 = *(const float4*)(wrow + cb);
    const float4 v1 = *(const float4*)(wrow + 32 + cb);
    uT[(cb + 0) * LDU + r] = v0.x;
    uT[(cb + 1) * LDU + r] = v0.y;
    uT[(cb + 2) * LDU + r] = v0.z;
    uT[(cb + 3) * LDU + r] = v0.w;
    uT[(cb + 32) * LDU + r] = v1.x;
    uT[(cb + 33) * LDU + r] = v1.y;
    uT[(cb + 34) * LDU + r] = v1.z;
    uT[(cb + 35) * LDU + r] = v1.w;
  }
  // stage xT: rows kt*64..+63 flat copy (8192 floats)
  {
    const float* xsrc = &x[(size_t)kt * 64 * DD];
#pragma unroll
    for (int p = 0; p < 4; ++p) {
      *(float4*)&xT[p * 2048 + t * 4] = *(const float4*)&xsrc[p * 2048 + t * 4];
    }
  }
  __syncthreads();
  const int w = t >> 6, l = t & 63;
  const int tx = l & 15, ly = l >> 4;
  const int d = (w & 1) * 64 + tx * 4;
  const int rg = (w >> 1) * 4 + ly;  // 0..15
  float acc[4][4] = {};
#pragma unroll 2
  for (int kb = 0; kb < 64; kb += 4) {
    float4 A[4], B[4];
#pragma unroll
    for (int q = 0; q < 4; ++q) {
      A[q] = *(const float4*)&uT[(kb + q) * LDU + rg * 4];
      B[q] = *(const float4*)&xT[(kb + q) * DD + d];
    }
#pragma unroll
    for (int q = 0; q < 4; ++q) {
      const float aa[4] = {A[q].x, A[q].y, A[q].z, A[q].w};
      const float bb[4] = {B[q].x, B[q].y, B[q].z, B[q].w};
#pragma unroll
      for (int i = 0; i < 4; ++i)
#pragma unroll
        for (int j = 0; j < 4; ++j) acc[i][j] = fmaf(aa[i], bb[j], acc[i][j]);
    }
  }
  const int row0 = rt * 64 + rg * 4;
#pragma unroll
  for (int i = 0; i < 4; ++i) {
    float4 s; s.x = acc[i][0]; s.y = acc[i][1]; s.z = acc[i][2]; s.w = acc[i][3];
    *(float4*)&Vp[((size_t)kt * NN + row0 + i) * DD + d] = s;
  }
}

// ---------------- K4: reduce partials + expmap/proj epilogue (proven) ----------------
__global__ __launch_bounds__(256) void k4_final(
    const float* __restrict__ x, const float* __restrict__ Vp,
    const float* __restrict__ PA, const float* __restrict__ nx2,
    float* __restrict__ out) {
  const int t = threadIdx.x;
  const int w = t >> 6;
  const int l = t & 63;
  const int row = blockIdx.x * 4 + w;

  float v0 = 0.0f, v1 = 0.0f;
#pragma unroll
  for (int kt = 0; kt < 16; ++kt) {
    const float2 vv = *(const float2*)&Vp[((size_t)kt * NN + row) * DD + 2 * l];
    v0 += vv.x;
    v1 += vv.y;
  }
  float sa = (l < 16) ? PA[row * 16 + l] : 0.0f;
#pragma unroll
  for (int m = 1; m < 64; m <<= 1) sa += __shfl_xor(sa, m, 64);

  const float nx2i = nx2[row];
  const float beta = 1.0f - nx2i;
  const float betac = fmaxf(beta, 1e-15f);
  const float2 xv = *(const float2*)&x[row * DD + 2 * l];
  const float xi0 = xv.x, xi1 = xv.y;
  const float u0 = beta * v0 - sa * xi0;
  const float u1 = beta * v1 - sa * xi1;
  float p0 = u0 * u0 + u1 * u1;
  float p1 = xi0 * u0 + xi1 * u1;
#pragma unroll
  for (int m = 1; m < 64; m <<= 1) {
    p0 += __shfl_xor(p0, m, 64);
    p1 += __shfl_xor(p1, m, 64);
  }
  const float un = fmaxf(sqrtf(p0), 1e-15f);
  const float lam = 2.0f / betac;
  const float tau = tanhf(0.5f * lam * un) / un;
  const float y2 = tau * tau * p0;
  const float xy = tau * p1;
  const float numx = 1.0f + 2.0f * xy + y2;
  const float dene = fmaxf(1.0f + 2.0f * xy + nx2i * y2, 1e-15f);
  float r0 = (numx * xi0 + beta * tau * u0) / dene;
  float r1 = (numx * xi1 + beta * tau * u1) / dene;
  const float n2 = numx * numx * nx2i + 2.0f * numx * beta * xy + beta * beta * y2;
  const float n = fmaxf(sqrtf(n2) / dene, 1e-15f);
  const float maxn = 1.0f - 4e-3f;
  if (n > maxn) {
    const float sc = maxn / n;
    r0 *= sc;
    r1 *= sc;
  }
  float2 ro; ro.x = r0; ro.y = r1;
  *(float2*)&out[row * DD + 2 * l] = ro;
}

// ---------------- Fallback: round-5 fused kernel (proven, 90 us) ----------------
__global__ __launch_bounds__(256) void hypagg_fused(
    const float* __restrict__ x, const float* __restrict__ adj,
    const float* __restrict__ aw, const float* __restrict__ bptr,
    float* __restrict__ out) {
  __shared__ __align__(16) float xi_lds[4 * DD];
  __shared__ __align__(16) float w2_lds[DD];
  const int t = threadIdx.x;
  const int w = t >> 6;
  const int l = t & 63;
  const int row = blockIdx.x * 4 + w;

  xi_lds[t] = x[blockIdx.x * 4 * DD + t];
  xi_lds[t + 256] = x[blockIdx.x * 4 * DD + t + 256];
  if (t < DD) w2_lds[t] = aw[DD + t];
  __syncthreads();

  const float attb = bptr[0];
  const float* xi = &xi_lds[w * DD];
  const float xi0 = xi[l];
  const float xi1 = xi[l + 64];

  float ra = xi0 * xi0 + xi1 * xi1;
  float rb = xi0 * aw[l] + xi1 * aw[l + 64];
#pragma unroll
  for (int m = 1; m < 64; m <<= 1) {
    ra += __shfl_xor(ra, m, 64);
    rb += __shfl_xor(rb, m, 64);
  }
  const float nx2i = ra;
  const float beta = 1.0f - nx2i;
  const float betac = fmaxf(beta, 1e-15f);
  const float hi = artanh_ratio(fmaxf(sqrtf(nx2i), 1e-15f));
  const float lfti = hi * rb;

  float V0 = 0.0f, V1 = 0.0f, SA = 0.0f;

  for (int j0 = 0; j0 < NN; j0 += 64) {
    const int jj = j0 + l;
    const float* xj = x + jj * DD;
    float s = 0.0f, ny2 = 0.0f, rj = 0.0f;
#pragma unroll 8
    for (int k4 = 0; k4 < DD / 4; ++k4) {
      const float4 b4 = *(const float4*)(xj + k4 * 4);
      const float4 a4 = *(const float4*)(xi + k4 * 4);
      const float4 w4 = *(const float4*)(&w2_lds[k4 * 4]);
      s   = fmaf(a4.x, b4.x, fmaf(a4.y, b4.y, fmaf(a4.z, b4.z, fmaf(a4.w, b4.w, s))));
      ny2 = fmaf(b4.x, b4.x, fmaf(b4.y, b4.y, fmaf(b4.z, b4.z, fmaf(b4.w, b4.w, ny2))));
      rj  = fmaf(w4.x, b4.x, fmaf(w4.y, b4.y, fmaf(w4.z, b4.z, fmaf(w4.w, b4.w, rj))));
    }
    const float hj = artanh_ratio(fmaxf(sqrtf(ny2), 1e-15f));
    const float rgtj = hj * rj;
    const float al = 1.0f - 2.0f * s + ny2;
    const float den = fmaxf(1.0f - 2.0f * s + nx2i * ny2, 1e-15f);
    float s2 = fmaxf(al * al * nx2i - 2.0f * al * beta * s + beta * beta * ny2, 0.0f);
    s2 = s2 / (den * den);
    const float sn = fmaxf(sqrtf(s2), 1e-15f);
    const float G = betac * artanh_ratio(sn);
    const float sig = 1.0f / (1.0f + expf(-(lfti + rgtj + attb)));
    const float u = sig * adj[row * NN + jj] * G / den;
    SA = fmaf(u, al, SA);
#pragma unroll 16
    for (int jq = 0; jq < 64; ++jq) {
      const float uq = __shfl(u, jq, 64);
      const float xd0 = x[(j0 + jq) * DD + l];
      const float xd1 = x[(j0 + jq) * DD + l + 64];
      V0 = fmaf(uq, xd0, V0);
      V1 = fmaf(uq, xd1, V1);
    }
  }

#pragma unroll
  for (int m = 1; m < 64; m <<= 1) SA += __shfl_xor(SA, m, 64);

  const float u0 = beta * V0 - SA * xi0;
  const float u1 = beta * V1 - SA * xi1;
  float p0 = u0 * u0 + u1 * u1;
  float p1 = xi0 * u0 + xi1 * u1;
#pragma unroll
  for (int m = 1; m < 64; m <<= 1) {
    p0 += __shfl_xor(p0, m, 64);
    p1 += __shfl_xor(p1, m, 64);
  }
  const float un = fmaxf(sqrtf(p0), 1e-15f);
  const float lam = 2.0f / betac;
  const float tau = tanhf(0.5f * lam * un) / un;
  const float y2 = tau * tau * p0;
  const float xy = tau * p1;
  const float numx = 1.0f + 2.0f * xy + y2;
  const float dene = fmaxf(1.0f + 2.0f * xy + nx2i * y2, 1e-15f);
  float r0 = (numx * xi0 + beta * tau * u0) / dene;
  float r1 = (numx * xi1 + beta * tau * u1) / dene;
  const float n2 = numx * numx * nx2i + 2.0f * numx * beta * xy + beta * beta * y2;
  const float n = fmaxf(sqrtf(n2) / dene, 1e-15f);
  const float maxn = 1.0f - 4e-3f;
  if (n > maxn) {
    const float sc = maxn / n;
    r0 *= sc;
    r1 *= sc;
  }
  out[row * DD + l] = r0;
  out[row * DD + l + 64] = r1;
}

extern "C" void kernel_launch(void* const* d_in, const int* in_sizes, int n_in,
                              void* d_out, int out_size, void* d_ws, size_t ws_size,
                              hipStream_t stream) {
  // Bind inputs BY SIZE (unique: x=131072, adj=1048576, att_w=256, att_b=1)
  const float* x = nullptr;
  const float* adj = nullptr;
  const float* aw = nullptr;
  const float* ab = nullptr;
  for (int i = 0; i < n_in; ++i) {
    switch (in_sizes[i]) {
      case NN * DD:  x   = (const float*)d_in[i]; break;
      case NN * NN:  adj = (const float*)d_in[i]; break;
      case 2 * DD:   aw  = (const float*)d_in[i]; break;
      case 1:        ab  = (const float*)d_in[i]; break;
      default: break;
    }
  }
  float* out = (float*)d_out;

  // ws layout: W [N*N] | Vp [16*N*D] | PA [N*16] | nx2,lft,rgt [3*N]
  const size_t need = ((size_t)NN * NN + 16 * (size_t)NN * DD + NN * 16 + 3 * NN) * sizeof(float);
  if (ws_size >= need) {
    float* W   = (float*)d_ws;
    float* Vp  = W + (size_t)NN * NN;
    float* PA  = Vp + 16 * (size_t)NN * DD;
    float* nx2 = PA + NN * 16;
    float* lft = nx2 + NN;
    float* rgt = lft + NN;
    hipLaunchKernelGGL(k1_scalars, dim3(NN / 4), dim3(256), 0, stream,
                       x, aw, nx2, lft, rgt);
    hipLaunchKernelGGL(k2_pairs, dim3(16, 16), dim3(256), 0, stream,
                       x, adj, ab, nx2, lft, rgt, W, PA);
    hipLaunchKernelGGL(k3_vpart, dim3(16, 16), dim3(512), 0, stream, x, W, Vp);
    hipLaunchKernelGGL(k4_final, dim3(NN / 4), dim3(256), 0, stream,
                       x, Vp, PA, nx2, out);
  } else {
    hipLaunchKernelGGL(hypagg_fused, dim3(NN / 4), dim3(256), 0, stream,
                       x, adj, aw, ab, out);
  }
}

// Round 10
// 33.456 us; speedup vs baseline: 3.1772x; 1.0645x over previous
//
#include <hip/hip_runtime.h>

#define NN 1024
#define DD 128
#define LDU 36  // uT k-stride in k3 (floats): 144B, 16B-aligned

// ---- fast math helpers ----
// v_rcp_f32 is ~1 ulp on gfx950; NO Newton step (NR turns inf into NaN:
// rcp(inf)=0 -> 0*(2-inf*0)=NaN). Raw rcp gives rcp(inf)=0 = correct limit.
__device__ __forceinline__ float frcp(float x) {
  return __builtin_amdgcn_rcpf(x);
}
__device__ __forceinline__ float fsqrt(float x) {
  return __builtin_amdgcn_sqrtf(x);
}
// artanh(z)/z with reference-style clipping (z >= 0)
__device__ __forceinline__ float artanh_ratio(float z) {
  z = fminf(z, 1.0f - 1e-7f);
  if (z < 1e-4f) return 1.0f + z * z * (1.0f / 3.0f);
  return 0.5f * (__logf(1.0f + z) - __logf(1.0f - z)) * frcp(z);
}
// tanh(a) for a >= 0 via exp(-2a) in [0,1]: overflow-free, saturates to 1.
__device__ __forceinline__ float ftanh(float a) {
  const float e = __expf(-2.0f * a);
  return (1.0f - e) * frcp(1.0f + e);
}

// ---------------- K1: per-node scalars ----------------
__global__ __launch_bounds__(256) void k1_scalars(
    const float* __restrict__ x, const float* __restrict__ aw,
    float* __restrict__ nx2, float* __restrict__ lft, float* __restrict__ rgt) {
  const int row = blockIdx.x * 4 + (threadIdx.x >> 6);
  const int l = threadIdx.x & 63;
  const float* xr = x + row * DD;
  float x0 = xr[l], x1 = xr[l + 64];
  float sa = x0 * x0 + x1 * x1;
  float sb = x0 * aw[l] + x1 * aw[l + 64];
  float sc = x0 * aw[DD + l] + x1 * aw[DD + l + 64];
#pragma unroll
  for (int m = 1; m < 64; m <<= 1) {
    sa += __shfl_xor(sa, m, 64);
    sb += __shfl_xor(sb, m, 64);
    sc += __shfl_xor(sc, m, 64);
  }
  if (l == 0) {
    float pn = fmaxf(fsqrt(sa), 1e-15f);
    float h = artanh_ratio(pn);
    nx2[row] = sa;
    lft[row] = h * sb;
    rgt[row] = h * sc;
  }
}

// ---------------- K2: tiled S-GEMM + pair epilogue ----------------
__global__ __launch_bounds__(256) void k2_pairs(
    const float* __restrict__ x, const float* __restrict__ adj,
    const float* __restrict__ bptr,
    const float* __restrict__ nx2, const float* __restrict__ lft,
    const float* __restrict__ rgt,
    float* __restrict__ W, float* __restrict__ PA) {
  __shared__ __align__(16) float xiT[DD * 64];
  __shared__ __align__(16) float xjT[DD * 64];
  const int t = threadIdx.x;
  const int bi = blockIdx.y, bj = blockIdx.x;
  const int tx = t & 15, ty = t >> 4;
  const int gi0 = bi * 64 + ty * 4;
  const int gj0 = bj * 64 + tx * 4;

  // prefetch epilogue operands into registers (hides latency under k-loop)
  float4 ajv[4];
  float xi2v[4], liv[4], ny2v[4], rv[4];
#pragma unroll
  for (int i = 0; i < 4; ++i) {
    ajv[i] = *(const float4*)&adj[(size_t)(gi0 + i) * NN + gj0];
    xi2v[i] = nx2[gi0 + i];
    liv[i] = lft[gi0 + i];
  }
#pragma unroll
  for (int j = 0; j < 4; ++j) { ny2v[j] = nx2[gj0 + j]; rv[j] = rgt[gj0 + j]; }
  const float attb = bptr[0];

  // stage k-major panels
  {
    const int r = t & 63;
    const int kq = t >> 6;  // k-quarter (32 k each)
    const float* si = x + (bi * 64 + r) * DD + kq * 32;
    const float* sj = x + (bj * 64 + r) * DD + kq * 32;
#pragma unroll
    for (int m = 0; m < 8; ++m) {
      const int k0 = kq * 32 + m * 4;
      const float4 vi = *(const float4*)(si + m * 4);
      const float4 vj = *(const float4*)(sj + m * 4);
      xiT[(k0 + 0) * 64 + r] = vi.x;
      xiT[(k0 + 1) * 64 + r] = vi.y;
      xiT[(k0 + 2) * 64 + r] = vi.z;
      xiT[(k0 + 3) * 64 + r] = vi.w;
      xjT[(k0 + 0) * 64 + r] = vj.x;
      xjT[(k0 + 1) * 64 + r] = vj.y;
      xjT[(k0 + 2) * 64 + r] = vj.z;
      xjT[(k0 + 3) * 64 + r] = vj.w;
    }
  }
  __syncthreads();
  float acc[4][4] = {};
#pragma unroll 2
  for (int kb = 0; kb < DD; kb += 4) {
    float4 A[4], B[4];
#pragma unroll
    for (int q = 0; q < 4; ++q) {
      A[q] = *(const float4*)&xiT[(kb + q) * 64 + ty * 4];
      B[q] = *(const float4*)&xjT[(kb + q) * 64 + tx * 4];
    }
#pragma unroll
    for (int q = 0; q < 4; ++q) {
      const float aa[4] = {A[q].x, A[q].y, A[q].z, A[q].w};
      const float bb[4] = {B[q].x, B[q].y, B[q].z, B[q].w};
#pragma unroll
      for (int i = 0; i < 4; ++i)
#pragma unroll
        for (int j = 0; j < 4; ++j) acc[i][j] = fmaf(aa[i], bb[j], acc[i][j]);
    }
  }
  // pair epilogue (fast-math; formulas proven rounds 5-8)
  float sua[4];
#pragma unroll
  for (int i = 0; i < 4; ++i) {
    const float xi2 = xi2v[i];
    const float li = liv[i];
    const float beta = 1.0f - xi2;
    const float betac = fmaxf(beta, 1e-15f);
    const float av[4] = {ajv[i].x, ajv[i].y, ajv[i].z, ajv[i].w};
    float u4[4];
    float ua = 0.0f;
#pragma unroll
    for (int j = 0; j < 4; ++j) {
      const float s = acc[i][j];
      const float al = 1.0f - 2.0f * s + ny2v[j];                      // alpha
      const float den = fmaxf(1.0f - 2.0f * s + xi2 * ny2v[j], 1e-15f);
      const float rden = frcp(den);
      float s2 = fmaxf(al * al * xi2 - 2.0f * al * beta * s + beta * beta * ny2v[j], 0.0f);
      s2 = s2 * rden * rden;                                            // |sub|^2
      const float sn = fmaxf(fsqrt(s2), 1e-15f);
      const float G = betac * artanh_ratio(sn);
      const float sig = frcp(1.0f + __expf(-(li + rv[j] + attb)));
      const float u = sig * av[j] * G * rden;
      u4[j] = u;
      ua = fmaf(u, al, ua);
    }
    float4 st; st.x = u4[0]; st.y = u4[1]; st.z = u4[2]; st.w = u4[3];
    *(float4*)&W[(size_t)(gi0 + i) * NN + gj0] = st;
    sua[i] = ua;
  }
#pragma unroll
  for (int m = 1; m < 16; m <<= 1) {
#pragma unroll
    for (int i = 0; i < 4; ++i) sua[i] += __shfl_xor(sua[i], m, 64);
  }
  if (tx == 0) {
#pragma unroll
    for (int i = 0; i < 4; ++i) PA[(gi0 + i) * 16 + bj] = sua[i];
  }
}

// ---------------- K3: V-partials GEMM (8 partials) ----------------
// Block (kt 0..7, rt 0..31): rows rt*32..+31, j-chunk kt*128..+127.
// uT [128j][32r] stride-36; xT [64j][128d] staged twice.
__global__ __launch_bounds__(256) void k3_vpart(
    const float* __restrict__ x, const float* __restrict__ W,
    float* __restrict__ Vp) {
  __shared__ __align__(16) float uT[128 * LDU];
  __shared__ __align__(16) float xT[64 * DD];
  const int t = threadIdx.x;
  const int kt = blockIdx.x, rt = blockIdx.y;
  // stage uT: coalesced W reads (8 thr/row x 16 floats), transposed write
  {
    const int r = t >> 3;          // 0..31
    const int c0 = (t & 7) * 16;   // 0,16,..,112
    const float* wrow = &W[(size_t)(rt * 32 + r) * NN + kt * 128 + c0];
#pragma unroll
    for (int m = 0; m < 4; ++m) {
      const float4 v = *(const float4*)(wrow + m * 4);
      uT[(c0 + m * 4 + 0) * LDU + r] = v.x;
      uT[(c0 + m * 4 + 1) * LDU + r] = v.y;
      uT[(c0 + m * 4 + 2) * LDU + r] = v.z;
      uT[(c0 + m * 4 + 3) * LDU + r] = v.w;
    }
  }
  const int tx = t & 31, ty = t >> 5;
  float acc[4][4] = {};
  for (int jh = 0; jh < 2; ++jh) {
    __syncthreads();  // pass 0: uT staged; pass 1: xT reads of pass 0 done
    {
      const float* xsrc = &x[(size_t)(kt * 128 + jh * 64) * DD];
#pragma unroll
      for (int p = 0; p < 8; ++p) {
        *(float4*)&xT[p * 1024 + t * 4] = *(const float4*)&xsrc[p * 1024 + t * 4];
      }
    }
    __syncthreads();
#pragma unroll 2
    for (int kb = 0; kb < 64; kb += 4) {
      float4 A[4], B[4];
#pragma unroll
      for (int q = 0; q < 4; ++q) {
        A[q] = *(const float4*)&uT[(jh * 64 + kb + q) * LDU + ty * 4];
        B[q] = *(const float4*)&xT[(kb + q) * DD + tx * 4];
      }
#pragma unroll
      for (int q = 0; q < 4; ++q) {
        const float aa[4] = {A[q].x, A[q].y, A[q].z, A[q].w};
        const float bb[4] = {B[q].x, B[q].y, B[q].z, B[q].w};
#pragma unroll
        for (int i = 0; i < 4; ++i)
#pragma unroll
          for (int j = 0; j < 4; ++j) acc[i][j] = fmaf(aa[i], bb[j], acc[i][j]);
      }
    }
  }
  const int row0 = rt * 32 + ty * 4;
#pragma unroll
  for (int i = 0; i < 4; ++i) {
    float4 s; s.x = acc[i][0]; s.y = acc[i][1]; s.z = acc[i][2]; s.w = acc[i][3];
    *(float4*)&Vp[((size_t)kt * NN + row0 + i) * DD + tx * 4] = s;
  }
}

// ---------------- K4: reduce 8 partials + expmap/proj epilogue ----------------
__global__ __launch_bounds__(256) void k4_final(
    const float* __restrict__ x, const float* __restrict__ Vp,
    const float* __restrict__ PA, const float* __restrict__ nx2,
    float* __restrict__ out) {
  const int t = threadIdx.x;
  const int w = t >> 6;
  const int l = t & 63;
  const int row = blockIdx.x * 4 + w;

  float v0 = 0.0f, v1 = 0.0f;
#pragma unroll
  for (int kt = 0; kt < 8; ++kt) {
    const float2 vv = *(const float2*)&Vp[((size_t)kt * NN + row) * DD + 2 * l];
    v0 += vv.x;
    v1 += vv.y;
  }
  float sa = (l < 16) ? PA[row * 16 + l] : 0.0f;
#pragma unroll
  for (int m = 1; m < 64; m <<= 1) sa += __shfl_xor(sa, m, 64);

  const float nx2i = nx2[row];
  const float beta = 1.0f - nx2i;
  const float betac = fmaxf(beta, 1e-15f);
  const float2 xv = *(const float2*)&x[row * DD + 2 * l];
  const float xi0 = xv.x, xi1 = xv.y;
  const float u0 = beta * v0 - sa * xi0;
  const float u1 = beta * v1 - sa * xi1;
  float p0 = u0 * u0 + u1 * u1;
  float p1 = xi0 * u0 + xi1 * u1;
#pragma unroll
  for (int m = 1; m < 64; m <<= 1) {
    p0 += __shfl_xor(p0, m, 64);
    p1 += __shfl_xor(p1, m, 64);
  }
  const float un = fmaxf(fsqrt(p0), 1e-15f);
  const float tau = ftanh(frcp(betac) * un) * frcp(un);  // tanh(0.5*lam*un)/un
  const float y2 = tau * tau * p0;
  const float xy = tau * p1;
  const float numx = 1.0f + 2.0f * xy + y2;
  const float dene = fmaxf(1.0f + 2.0f * xy + nx2i * y2, 1e-15f);
  const float rdene = frcp(dene);
  float r0 = (numx * xi0 + beta * tau * u0) * rdene;
  float r1 = (numx * xi1 + beta * tau * u1) * rdene;
  const float n2 = fmaxf(numx * numx * nx2i + 2.0f * numx * beta * xy + beta * beta * y2, 0.0f);
  const float n = fmaxf(fsqrt(n2) * rdene, 1e-15f);
  const float maxn = 1.0f - 4e-3f;  // (1-PROJ_EPS)/sqrt(c)
  if (n > maxn) {
    const float sc = maxn * frcp(n);
    r0 *= sc;
    r1 *= sc;
  }
  float2 ro; ro.x = r0; ro.y = r1;
  *(float2*)&out[row * DD + 2 * l] = ro;
}

// ---------------- Fallback: fused kernel (proven structure) ----------------
__global__ __launch_bounds__(256) void hypagg_fused(
    const float* __restrict__ x, const float* __restrict__ adj,
    const float* __restrict__ aw, const float* __restrict__ bptr,
    float* __restrict__ out) {
  __shared__ __align__(16) float xi_lds[4 * DD];
  __shared__ __align__(16) float w2_lds[DD];
  const int t = threadIdx.x;
  const int w = t >> 6;
  const int l = t & 63;
  const int row = blockIdx.x * 4 + w;

  xi_lds[t] = x[blockIdx.x * 4 * DD + t];
  xi_lds[t + 256] = x[blockIdx.x * 4 * DD + t + 256];
  if (t < DD) w2_lds[t] = aw[DD + t];
  __syncthreads();

  const float attb = bptr[0];
  const float* xi = &xi_lds[w * DD];
  const float xi0 = xi[l];
  const float xi1 = xi[l + 64];

  float ra = xi0 * xi0 + xi1 * xi1;
  float rb = xi0 * aw[l] + xi1 * aw[l + 64];
#pragma unroll
  for (int m = 1; m < 64; m <<= 1) {
    ra += __shfl_xor(ra, m, 64);
    rb += __shfl_xor(rb, m, 64);
  }
  const float nx2i = ra;
  const float beta = 1.0f - nx2i;
  const float betac = fmaxf(beta, 1e-15f);
  const float hi = artanh_ratio(fmaxf(fsqrt(nx2i), 1e-15f));
  const float lfti = hi * rb;

  float V0 = 0.0f, V1 = 0.0f, SA = 0.0f;

  for (int j0 = 0; j0 < NN; j0 += 64) {
    const int jj = j0 + l;
    const float* xj = x + jj * DD;
    float s = 0.0f, ny2 = 0.0f, rj = 0.0f;
#pragma unroll 8
    for (int k4 = 0; k4 < DD / 4; ++k4) {
      const float4 b4 = *(const float4*)(xj + k4 * 4);
      const float4 a4 = *(const float4*)(xi + k4 * 4);
      const float4 w4 = *(const float4*)(&w2_lds[k4 * 4]);
      s   = fmaf(a4.x, b4.x, fmaf(a4.y, b4.y, fmaf(a4.z, b4.z, fmaf(a4.w, b4.w, s))));
      ny2 = fmaf(b4.x, b4.x, fmaf(b4.y, b4.y, fmaf(b4.z, b4.z, fmaf(b4.w, b4.w, ny2))));
      rj  = fmaf(w4.x, b4.x, fmaf(w4.y, b4.y, fmaf(w4.z, b4.z, fmaf(w4.w, b4.w, rj))));
    }
    const float hj = artanh_ratio(fmaxf(fsqrt(ny2), 1e-15f));
    const float rgtj = hj * rj;
    const float al = 1.0f - 2.0f * s + ny2;
    const float den = fmaxf(1.0f - 2.0f * s + nx2i * ny2, 1e-15f);
    const float rden = frcp(den);
    float s2 = fmaxf(al * al * nx2i - 2.0f * al * beta * s + beta * beta * ny2, 0.0f);
    s2 = s2 * rden * rden;
    const float sn = fmaxf(fsqrt(s2), 1e-15f);
    const float G = betac * artanh_ratio(sn);
    const float sig = frcp(1.0f + __expf(-(lfti + rgtj + attb)));
    const float u = sig * adj[row * NN + jj] * G * rden;
    SA = fmaf(u, al, SA);
#pragma unroll 16
    for (int jq = 0; jq < 64; ++jq) {
      const float uq = __shfl(u, jq, 64);
      const float xd0 = x[(j0 + jq) * DD + l];
      const float xd1 = x[(j0 + jq) * DD + l + 64];
      V0 = fmaf(uq, xd0, V0);
      V1 = fmaf(uq, xd1, V1);
    }
  }

#pragma unroll
  for (int m = 1; m < 64; m <<= 1) SA += __shfl_xor(SA, m, 64);

  const float u0 = beta * V0 - SA * xi0;
  const float u1 = beta * V1 - SA * xi1;
  float p0 = u0 * u0 + u1 * u1;
  float p1 = xi0 * u0 + xi1 * u1;
#pragma unroll
  for (int m = 1; m < 64; m <<= 1) {
    p0 += __shfl_xor(p0, m, 64);
    p1 += __shfl_xor(p1, m, 64);
  }
  const float un = fmaxf(fsqrt(p0), 1e-15f);
  const float tau = ftanh(frcp(betac) * un) * frcp(un);
  const float y2 = tau * tau * p0;
  const float xy = tau * p1;
  const float numx = 1.0f + 2.0f * xy + y2;
  const float dene = fmaxf(1.0f + 2.0f * xy + nx2i * y2, 1e-15f);
  const float rdene = frcp(dene);
  float r0 = (numx * xi0 + beta * tau * u0) * rdene;
  float r1 = (numx * xi1 + beta * tau * u1) * rdene;
  const float n2 = fmaxf(numx * numx * nx2i + 2.0f * numx * beta * xy + beta * beta * y2, 0.0f);
  const float n = fmaxf(fsqrt(n2) * rdene, 1e-15f);
  const float maxn = 1.0f - 4e-3f;
  if (n > maxn) {
    const float sc = maxn * frcp(n);
    r0 *= sc;
    r1 *= sc;
  }
  out[row * DD + l] = r0;
  out[row * DD + l + 64] = r1;
}

extern "C" void kernel_launch(void* const* d_in, const int* in_sizes, int n_in,
                              void* d_out, int out_size, void* d_ws, size_t ws_size,
                              hipStream_t stream) {
  // Bind inputs BY SIZE (unique: x=131072, adj=1048576, att_w=256, att_b=1)
  const float* x = nullptr;
  const float* adj = nullptr;
  const float* aw = nullptr;
  const float* ab = nullptr;
  for (int i = 0; i < n_in; ++i) {
    switch (in_sizes[i]) {
      case NN * DD:  x   = (const float*)d_in[i]; break;
      case NN * NN:  adj = (const float*)d_in[i]; break;
      case 2 * DD:   aw  = (const float*)d_in[i]; break;
      case 1:        ab  = (const float*)d_in[i]; break;
      default: break;
    }
  }
  float* out = (float*)d_out;

  // ws layout: W [N*N] | Vp [8*N*D] | PA [N*16] | nx2,lft,rgt [3*N]
  const size_t need = ((size_t)NN * NN + 8 * (size_t)NN * DD + NN * 16 + 3 * NN) * sizeof(float);
  if (ws_size >= need) {
    float* W   = (float*)d_ws;
    float* Vp  = W + (size_t)NN * NN;
    float* PA  = Vp + 8 * (size_t)NN * DD;
    float* nx2 = PA + NN * 16;
    float* lft = nx2 + NN;
    float* rgt = lft + NN;
    hipLaunchKernelGGL(k1_scalars, dim3(NN / 4), dim3(256), 0, stream,
                       x, aw, nx2, lft, rgt);
    hipLaunchKernelGGL(k2_pairs, dim3(16, 16), dim3(256), 0, stream,
                       x, adj, ab, nx2, lft, rgt, W, PA);
    hipLaunchKernelGGL(k3_vpart, dim3(8, 32), dim3(256), 0, stream, x, W, Vp);
    hipLaunchKernelGGL(k4_final, dim3(NN / 4), dim3(256), 0, stream,
                       x, Vp, PA, nx2, out);
  } else {
    hipLaunchKernelGGL(hypagg_fused, dim3(NN / 4), dim3(256), 0, stream,
                       x, adj, aw, ab, out);
  }
}

// Round 11
// 29.735 us; speedup vs baseline: 3.5748x; 1.1251x over previous
//
#include <hip/hip_runtime.h>

#define NN 1024
#define DD 128
#define LDU 36  // uT k-stride in k3 (floats): 144B, 16B-aligned

// ---- fast math helpers ----
// v_rcp_f32 is ~1 ulp on gfx950; NO Newton step (NR turns inf into NaN:
// rcp(inf)=0 -> 0*(2-inf*0)=NaN). Raw rcp gives rcp(inf)=0 = correct limit.
__device__ __forceinline__ float frcp(float x) {
  return __builtin_amdgcn_rcpf(x);
}
__device__ __forceinline__ float fsqrt(float x) {
  return __builtin_amdgcn_sqrtf(x);
}
// artanh(z)/z with reference-style clipping (z >= 0)
__device__ __forceinline__ float artanh_ratio(float z) {
  z = fminf(z, 1.0f - 1e-7f);
  if (z < 1e-4f) return 1.0f + z * z * (1.0f / 3.0f);
  return 0.5f * (__logf(1.0f + z) - __logf(1.0f - z)) * frcp(z);
}
// tanh(a) for a >= 0 via exp(-2a) in [0,1]: overflow-free, saturates to 1.
__device__ __forceinline__ float ftanh(float a) {
  const float e = __expf(-2.0f * a);
  return (1.0f - e) * frcp(1.0f + e);
}

// ---------------- K2: fused per-node scalars + tiled S-GEMM + pair epilogue ----------------
// Scalar phase replaces the old k1: each block computes nx2/lft for its 64
// i-rows and nx2/rgt for its 64 j-rows from the LDS panels it already staged.
__global__ __launch_bounds__(256) void k2_pairs(
    const float* __restrict__ x, const float* __restrict__ adj,
    const float* __restrict__ aw, const float* __restrict__ bptr,
    float* __restrict__ W, float* __restrict__ PA) {
  __shared__ __align__(16) float xiT[DD * 64];
  __shared__ __align__(16) float xjT[DD * 64];
  __shared__ float s_nx2i[64], s_lft[64], s_nx2j[64], s_rgt[64];
  const int t = threadIdx.x;
  const int bi = blockIdx.y, bj = blockIdx.x;
  const int tx = t & 15, ty = t >> 4;
  const int gi0 = bi * 64 + ty * 4;
  const int gj0 = bj * 64 + tx * 4;

  // prefetch adj tile rows into registers (hides latency under k-loop)
  float4 ajv[4];
#pragma unroll
  for (int i = 0; i < 4; ++i) {
    ajv[i] = *(const float4*)&adj[(size_t)(gi0 + i) * NN + gj0];
  }
  const float attb = bptr[0];

  // stage k-major panels
  {
    const int r = t & 63;
    const int kq = t >> 6;  // k-quarter (32 k each)
    const float* si = x + (bi * 64 + r) * DD + kq * 32;
    const float* sj = x + (bj * 64 + r) * DD + kq * 32;
#pragma unroll
    for (int m = 0; m < 8; ++m) {
      const int k0 = kq * 32 + m * 4;
      const float4 vi = *(const float4*)(si + m * 4);
      const float4 vj = *(const float4*)(sj + m * 4);
      xiT[(k0 + 0) * 64 + r] = vi.x;
      xiT[(k0 + 1) * 64 + r] = vi.y;
      xiT[(k0 + 2) * 64 + r] = vi.z;
      xiT[(k0 + 3) * 64 + r] = vi.w;
      xjT[(k0 + 0) * 64 + r] = vj.x;
      xjT[(k0 + 1) * 64 + r] = vj.y;
      xjT[(k0 + 2) * 64 + r] = vj.z;
      xjT[(k0 + 3) * 64 + r] = vj.w;
    }
  }
  __syncthreads();

  // scalar phase: thread-pair per row, k split in halves, shfl-combine.
  // waves 0-1 -> i-panel rows (nx2, lft=h*(x.w1)); waves 2-3 -> j-panel
  // rows (nx2, rgt=h*(x.w2)).
  {
    const int r = (t >> 1) & 63;
    const int h = t & 1;
    const bool jp = (t >= 128);
    const float* panel = jp ? xjT : xiT;
    const float* wv = aw + (jp ? DD : 0);
    float sa = 0.0f, sb = 0.0f;
    const int k0 = h * 64;
#pragma unroll 8
    for (int k = 0; k < 64; ++k) {
      const float v = panel[(k0 + k) * 64 + r];
      sa = fmaf(v, v, sa);
      sb = fmaf(v, wv[k0 + k], sb);
    }
    sa += __shfl_xor(sa, 1, 64);
    sb += __shfl_xor(sb, 1, 64);
    if (h == 0) {
      const float pn = fmaxf(fsqrt(sa), 1e-15f);
      const float hh = artanh_ratio(pn);
      if (jp) { s_nx2j[r] = sa; s_rgt[r] = hh * sb; }
      else    { s_nx2i[r] = sa; s_lft[r] = hh * sb; }
    }
  }
  __syncthreads();

  float acc[4][4] = {};
#pragma unroll 2
  for (int kb = 0; kb < DD; kb += 4) {
    float4 A[4], B[4];
#pragma unroll
    for (int q = 0; q < 4; ++q) {
      A[q] = *(const float4*)&xiT[(kb + q) * 64 + ty * 4];
      B[q] = *(const float4*)&xjT[(kb + q) * 64 + tx * 4];
    }
#pragma unroll
    for (int q = 0; q < 4; ++q) {
      const float aa[4] = {A[q].x, A[q].y, A[q].z, A[q].w};
      const float bb[4] = {B[q].x, B[q].y, B[q].z, B[q].w};
#pragma unroll
      for (int i = 0; i < 4; ++i)
#pragma unroll
        for (int j = 0; j < 4; ++j) acc[i][j] = fmaf(aa[i], bb[j], acc[i][j]);
    }
  }
  // pair epilogue (fast-math; formulas proven rounds 5-10)
  float ny2v[4], rv[4];
#pragma unroll
  for (int j = 0; j < 4; ++j) {
    ny2v[j] = s_nx2j[tx * 4 + j];
    rv[j] = s_rgt[tx * 4 + j];
  }
  float sua[4];
#pragma unroll
  for (int i = 0; i < 4; ++i) {
    const float xi2 = s_nx2i[ty * 4 + i];
    const float li = s_lft[ty * 4 + i];
    const float beta = 1.0f - xi2;
    const float betac = fmaxf(beta, 1e-15f);
    const float av[4] = {ajv[i].x, ajv[i].y, ajv[i].z, ajv[i].w};
    float u4[4];
    float ua = 0.0f;
#pragma unroll
    for (int j = 0; j < 4; ++j) {
      const float s = acc[i][j];
      const float al = 1.0f - 2.0f * s + ny2v[j];                      // alpha
      const float den = fmaxf(1.0f - 2.0f * s + xi2 * ny2v[j], 1e-15f);
      const float rden = frcp(den);
      float s2 = fmaxf(al * al * xi2 - 2.0f * al * beta * s + beta * beta * ny2v[j], 0.0f);
      s2 = s2 * rden * rden;                                            // |sub|^2
      const float sn = fmaxf(fsqrt(s2), 1e-15f);
      const float G = betac * artanh_ratio(sn);
      const float sig = frcp(1.0f + __expf(-(li + rv[j] + attb)));
      const float u = sig * av[j] * G * rden;
      u4[j] = u;
      ua = fmaf(u, al, ua);
    }
    float4 st; st.x = u4[0]; st.y = u4[1]; st.z = u4[2]; st.w = u4[3];
    *(float4*)&W[(size_t)(gi0 + i) * NN + gj0] = st;
    sua[i] = ua;
  }
#pragma unroll
  for (int m = 1; m < 16; m <<= 1) {
#pragma unroll
    for (int i = 0; i < 4; ++i) sua[i] += __shfl_xor(sua[i], m, 64);
  }
  if (tx == 0) {
#pragma unroll
    for (int i = 0; i < 4; ++i) PA[(gi0 + i) * 16 + bj] = sua[i];
  }
}

// ---------------- K3: V-partials GEMM (8 partials) ----------------
// Block (kt 0..7, rt 0..31): rows rt*32..+31, j-chunk kt*128..+127.
// uT [128j][32r] stride-36; xT [64j][128d] staged twice.
__global__ __launch_bounds__(256) void k3_vpart(
    const float* __restrict__ x, const float* __restrict__ W,
    float* __restrict__ Vp) {
  __shared__ __align__(16) float uT[128 * LDU];
  __shared__ __align__(16) float xT[64 * DD];
  const int t = threadIdx.x;
  const int kt = blockIdx.x, rt = blockIdx.y;
  // stage uT: coalesced W reads (8 thr/row x 16 floats), transposed write
  {
    const int r = t >> 3;          // 0..31
    const int c0 = (t & 7) * 16;   // 0,16,..,112
    const float* wrow = &W[(size_t)(rt * 32 + r) * NN + kt * 128 + c0];
#pragma unroll
    for (int m = 0; m < 4; ++m) {
      const float4 v = *(const float4*)(wrow + m * 4);
      uT[(c0 + m * 4 + 0) * LDU + r] = v.x;
      uT[(c0 + m * 4 + 1) * LDU + r] = v.y;
      uT[(c0 + m * 4 + 2) * LDU + r] = v.z;
      uT[(c0 + m * 4 + 3) * LDU + r] = v.w;
    }
  }
  const int tx = t & 31, ty = t >> 5;
  float acc[4][4] = {};
  for (int jh = 0; jh < 2; ++jh) {
    __syncthreads();  // pass 0: uT staged; pass 1: xT reads of pass 0 done
    {
      const float* xsrc = &x[(size_t)(kt * 128 + jh * 64) * DD];
#pragma unroll
      for (int p = 0; p < 8; ++p) {
        *(float4*)&xT[p * 1024 + t * 4] = *(const float4*)&xsrc[p * 1024 + t * 4];
      }
    }
    __syncthreads();
#pragma unroll 2
    for (int kb = 0; kb < 64; kb += 4) {
      float4 A[4], B[4];
#pragma unroll
      for (int q = 0; q < 4; ++q) {
        A[q] = *(const float4*)&uT[(jh * 64 + kb + q) * LDU + ty * 4];
        B[q] = *(const float4*)&xT[(kb + q) * DD + tx * 4];
      }
#pragma unroll
      for (int q = 0; q < 4; ++q) {
        const float aa[4] = {A[q].x, A[q].y, A[q].z, A[q].w};
        const float bb[4] = {B[q].x, B[q].y, B[q].z, B[q].w};
#pragma unroll
        for (int i = 0; i < 4; ++i)
#pragma unroll
          for (int j = 0; j < 4; ++j) acc[i][j] = fmaf(aa[i], bb[j], acc[i][j]);
      }
    }
  }
  const int row0 = rt * 32 + ty * 4;
#pragma unroll
  for (int i = 0; i < 4; ++i) {
    float4 s; s.x = acc[i][0]; s.y = acc[i][1]; s.z = acc[i][2]; s.w = acc[i][3];
    *(float4*)&Vp[((size_t)kt * NN + row0 + i) * DD + tx * 4] = s;
  }
}

// ---------------- K4: reduce 8 partials + expmap/proj (recomputes nx2) ----------------
__global__ __launch_bounds__(256) void k4_final(
    const float* __restrict__ x, const float* __restrict__ Vp,
    const float* __restrict__ PA, float* __restrict__ out) {
  const int t = threadIdx.x;
  const int w = t >> 6;
  const int l = t & 63;
  const int row = blockIdx.x * 4 + w;

  const float2 xv = *(const float2*)&x[row * DD + 2 * l];
  const float xi0 = xv.x, xi1 = xv.y;
  float ra = xi0 * xi0 + xi1 * xi1;
#pragma unroll
  for (int m = 1; m < 64; m <<= 1) ra += __shfl_xor(ra, m, 64);
  const float nx2i = ra;

  float v0 = 0.0f, v1 = 0.0f;
#pragma unroll
  for (int kt = 0; kt < 8; ++kt) {
    const float2 vv = *(const float2*)&Vp[((size_t)kt * NN + row) * DD + 2 * l];
    v0 += vv.x;
    v1 += vv.y;
  }
  float sa = (l < 16) ? PA[row * 16 + l] : 0.0f;
#pragma unroll
  for (int m = 1; m < 64; m <<= 1) sa += __shfl_xor(sa, m, 64);

  const float beta = 1.0f - nx2i;
  const float betac = fmaxf(beta, 1e-15f);
  const float u0 = beta * v0 - sa * xi0;
  const float u1 = beta * v1 - sa * xi1;
  float p0 = u0 * u0 + u1 * u1;
  float p1 = xi0 * u0 + xi1 * u1;
#pragma unroll
  for (int m = 1; m < 64; m <<= 1) {
    p0 += __shfl_xor(p0, m, 64);
    p1 += __shfl_xor(p1, m, 64);
  }
  const float un = fmaxf(fsqrt(p0), 1e-15f);
  const float tau = ftanh(frcp(betac) * un) * frcp(un);  // tanh(0.5*lam*un)/un
  const float y2 = tau * tau * p0;
  const float xy = tau * p1;
  const float numx = 1.0f + 2.0f * xy + y2;
  const float dene = fmaxf(1.0f + 2.0f * xy + nx2i * y2, 1e-15f);
  const float rdene = frcp(dene);
  float r0 = (numx * xi0 + beta * tau * u0) * rdene;
  float r1 = (numx * xi1 + beta * tau * u1) * rdene;
  const float n2 = fmaxf(numx * numx * nx2i + 2.0f * numx * beta * xy + beta * beta * y2, 0.0f);
  const float n = fmaxf(fsqrt(n2) * rdene, 1e-15f);
  const float maxn = 1.0f - 4e-3f;  // (1-PROJ_EPS)/sqrt(c)
  if (n > maxn) {
    const float sc = maxn * frcp(n);
    r0 *= sc;
    r1 *= sc;
  }
  float2 ro; ro.x = r0; ro.y = r1;
  *(float2*)&out[row * DD + 2 * l] = ro;
}

// ---------------- Fallback: fused kernel (proven structure) ----------------
__global__ __launch_bounds__(256) void hypagg_fused(
    const float* __restrict__ x, const float* __restrict__ adj,
    const float* __restrict__ aw, const float* __restrict__ bptr,
    float* __restrict__ out) {
  __shared__ __align__(16) float xi_lds[4 * DD];
  __shared__ __align__(16) float w2_lds[DD];
  const int t = threadIdx.x;
  const int w = t >> 6;
  const int l = t & 63;
  const int row = blockIdx.x * 4 + w;

  xi_lds[t] = x[blockIdx.x * 4 * DD + t];
  xi_lds[t + 256] = x[blockIdx.x * 4 * DD + t + 256];
  if (t < DD) w2_lds[t] = aw[DD + t];
  __syncthreads();

  const float attb = bptr[0];
  const float* xi = &xi_lds[w * DD];
  const float xi0 = xi[l];
  const float xi1 = xi[l + 64];

  float ra = xi0 * xi0 + xi1 * xi1;
  float rb = xi0 * aw[l] + xi1 * aw[l + 64];
#pragma unroll
  for (int m = 1; m < 64; m <<= 1) {
    ra += __shfl_xor(ra, m, 64);
    rb += __shfl_xor(rb, m, 64);
  }
  const float nx2i = ra;
  const float beta = 1.0f - nx2i;
  const float betac = fmaxf(beta, 1e-15f);
  const float hi = artanh_ratio(fmaxf(fsqrt(nx2i), 1e-15f));
  const float lfti = hi * rb;

  float V0 = 0.0f, V1 = 0.0f, SA = 0.0f;

  for (int j0 = 0; j0 < NN; j0 += 64) {
    const int jj = j0 + l;
    const float* xj = x + jj * DD;
    float s = 0.0f, ny2 = 0.0f, rj = 0.0f;
#pragma unroll 8
    for (int k4 = 0; k4 < DD / 4; ++k4) {
      const float4 b4 = *(const float4*)(xj + k4 * 4);
      const float4 a4 = *(const float4*)(xi + k4 * 4);
      const float4 w4 = *(const float4*)(&w2_lds[k4 * 4]);
      s   = fmaf(a4.x, b4.x, fmaf(a4.y, b4.y, fmaf(a4.z, b4.z, fmaf(a4.w, b4.w, s))));
      ny2 = fmaf(b4.x, b4.x, fmaf(b4.y, b4.y, fmaf(b4.z, b4.z, fmaf(b4.w, b4.w, ny2))));
      rj  = fmaf(w4.x, b4.x, fmaf(w4.y, b4.y, fmaf(w4.z, b4.z, fmaf(w4.w, b4.w, rj))));
    }
    const float hj = artanh_ratio(fmaxf(fsqrt(ny2), 1e-15f));
    const float rgtj = hj * rj;
    const float al = 1.0f - 2.0f * s + ny2;
    const float den = fmaxf(1.0f - 2.0f * s + nx2i * ny2, 1e-15f);
    const float rden = frcp(den);
    float s2 = fmaxf(al * al * nx2i - 2.0f * al * beta * s + beta * beta * ny2, 0.0f);
    s2 = s2 * rden * rden;
    const float sn = fmaxf(fsqrt(s2), 1e-15f);
    const float G = betac * artanh_ratio(sn);
    const float sig = frcp(1.0f + __expf(-(lfti + rgtj + attb)));
    const float u = sig * adj[row * NN + jj] * G * rden;
    SA = fmaf(u, al, SA);
#pragma unroll 16
    for (int jq = 0; jq < 64; ++jq) {
      const float uq = __shfl(u, jq, 64);
      const float xd0 = x[(j0 + jq) * DD + l];
      const float xd1 = x[(j0 + jq) * DD + l + 64];
      V0 = fmaf(uq, xd0, V0);
      V1 = fmaf(uq, xd1, V1);
    }
  }

#pragma unroll
  for (int m = 1; m < 64; m <<= 1) SA += __shfl_xor(SA, m, 64);

  const float u0 = beta * V0 - SA * xi0;
  const float u1 = beta * V1 - SA * xi1;
  float p0 = u0 * u0 + u1 * u1;
  float p1 = xi0 * u0 + xi1 * u1;
#pragma unroll
  for (int m = 1; m < 64; m <<= 1) {
    p0 += __shfl_xor(p0, m, 64);
    p1 += __shfl_xor(p1, m, 64);
  }
  const float un = fmaxf(fsqrt(p0), 1e-15f);
  const float tau = ftanh(frcp(betac) * un) * frcp(un);
  const float y2 = tau * tau * p0;
  const float xy = tau * p1;
  const float numx = 1.0f + 2.0f * xy + y2;
  const float dene = fmaxf(1.0f + 2.0f * xy + nx2i * y2, 1e-15f);
  const float rdene = frcp(dene);
  float r0 = (numx * xi0 + beta * tau * u0) * rdene;
  float r1 = (numx * xi1 + beta * tau * u1) * rdene;
  const float n2 = fmaxf(numx * numx * nx2i + 2.0f * numx * beta * xy + beta * beta * y2, 0.0f);
  const float n = fmaxf(fsqrt(n2) * rdene, 1e-15f);
  const float maxn = 1.0f - 4e-3f;
  if (n > maxn) {
    const float sc = maxn * frcp(n);
    r0 *= sc;
    r1 *= sc;
  }
  out[row * DD + l] = r0;
  out[row * DD + l + 64] = r1;
}

extern "C" void kernel_launch(void* const* d_in, const int* in_sizes, int n_in,
                              void* d_out, int out_size, void* d_ws, size_t ws_size,
                              hipStream_t stream) {
  // Bind inputs BY SIZE (unique: x=131072, adj=1048576, att_w=256, att_b=1)
  const float* x = nullptr;
  const float* adj = nullptr;
  const float* aw = nullptr;
  const float* ab = nullptr;
  for (int i = 0; i < n_in; ++i) {
    switch (in_sizes[i]) {
      case NN * DD:  x   = (const float*)d_in[i]; break;
      case NN * NN:  adj = (const float*)d_in[i]; break;
      case 2 * DD:   aw  = (const float*)d_in[i]; break;
      case 1:        ab  = (const float*)d_in[i]; break;
      default: break;
    }
  }
  float* out = (float*)d_out;

  // ws layout: W [N*N] | Vp [8*N*D] | PA [N*16]
  const size_t need = ((size_t)NN * NN + 8 * (size_t)NN * DD + NN * 16) * sizeof(float);
  if (ws_size >= need) {
    float* W  = (float*)d_ws;
    float* Vp = W + (size_t)NN * NN;
    float* PA = Vp + 8 * (size_t)NN * DD;
    hipLaunchKernelGGL(k2_pairs, dim3(16, 16), dim3(256), 0, stream,
                       x, adj, aw, ab, W, PA);
    hipLaunchKernelGGL(k3_vpart, dim3(8, 32), dim3(256), 0, stream, x, W, Vp);
    hipLaunchKernelGGL(k4_final, dim3(NN / 4), dim3(256), 0, stream,
                       x, Vp, PA, out);
  } else {
    hipLaunchKernelGGL(hypagg_fused, dim3(NN / 4), dim3(256), 0, stream,
                       x, adj, aw, ab, out);
  }
}